// Round 1
// baseline (311.071 us; speedup 1.0000x reference)
//
#include <hip/hip_runtime.h>
#include <hip/hip_bf16.h>

// Problem constants
#define BATCH 8
#define NN 2048
#define IN_F 256
#define OUT_F 128
#define ALPHA 0.2f

// ---------------------------------------------------------------------------
// Kernel 1: projections.
//   Wh = h @ W1, Wj = j @ W2  (per-row GEMV, K=256, 128 outputs)
//   V  = Wh + Wj              -> ws
//   s1 = Wh . a[:128]         -> ws
//   s2 = Wh . a[128:]         -> ws
// Block: 256 threads, 16 rows. Each thread owns one output column o for 8 rows.
// ---------------------------------------------------------------------------
#define ROWS1 16

__global__ __launch_bounds__(256) void k_proj(
    const float* __restrict__ h, const float* __restrict__ j,
    const float* __restrict__ W1, const float* __restrict__ W2,
    const float* __restrict__ a,
    float* __restrict__ V, float* __restrict__ s1, float* __restrict__ s2)
{
    __shared__ float h_lds[ROWS1 * IN_F];    // 16 KB
    __shared__ float j_lds[ROWS1 * IN_F];    // 16 KB
    __shared__ float wh_lds[ROWS1 * OUT_F];  // 8 KB
    __shared__ float a_lds[2 * OUT_F];       // 1 KB

    const int t = threadIdx.x;
    const long long row0 = (long long)blockIdx.x * ROWS1;  // global row = b*N + n

    const float* hbase = h + row0 * IN_F;
    const float* jbase = j + row0 * IN_F;
    for (int idx = t; idx < ROWS1 * IN_F; idx += 256) {
        h_lds[idx] = hbase[idx];
        j_lds[idx] = jbase[idx];
    }
    if (t < 2 * OUT_F) a_lds[t] = a[t];
    __syncthreads();

    const int o    = t & (OUT_F - 1);
    const int half = t >> 7;  // 0 or 1 -> rows half*8 .. half*8+7

    float acch[8], accj[8];
#pragma unroll
    for (int r = 0; r < 8; ++r) { acch[r] = 0.f; accj[r] = 0.f; }

    const float* w1p = W1 + o;  // W1[k][o], stride OUT_F
    const float* w2p = W2 + o;

#pragma unroll 4
    for (int k = 0; k < IN_F; ++k) {
        const float w1 = w1p[k * OUT_F];
        const float w2 = w2p[k * OUT_F];
#pragma unroll
        for (int r = 0; r < 8; ++r) {
            const float hv = h_lds[(half * 8 + r) * IN_F + k];  // LDS broadcast
            const float jv = j_lds[(half * 8 + r) * IN_F + k];
            acch[r] = fmaf(hv, w1, acch[r]);
            accj[r] = fmaf(jv, w2, accj[r]);
        }
    }

#pragma unroll
    for (int r = 0; r < 8; ++r) {
        const int rr = half * 8 + r;
        wh_lds[rr * OUT_F + o] = acch[r];
        V[(row0 + rr) * OUT_F + o] = acch[r] + accj[r];
    }
    __syncthreads();

    // s1/s2: dot(Wh[row], a1/a2). Wave w reduces rows 4w..4w+3.
    const int wave = t >> 6, lane = t & 63;
#pragma unroll
    for (int q = 0; q < 4; ++q) {
        const int rr = wave * 4 + q;
        float v1 = wh_lds[rr * OUT_F + lane] * a_lds[lane]
                 + wh_lds[rr * OUT_F + lane + 64] * a_lds[lane + 64];
        float v2 = wh_lds[rr * OUT_F + lane] * a_lds[OUT_F + lane]
                 + wh_lds[rr * OUT_F + lane + 64] * a_lds[OUT_F + lane + 64];
#pragma unroll
        for (int off = 32; off; off >>= 1) {
            v1 += __shfl_down(v1, off);
            v2 += __shfl_down(v2, off);
        }
        if (lane == 0) { s1[row0 + rr] = v1; s2[row0 + rr] = v2; }
    }
}

// ---------------------------------------------------------------------------
// Kernel 2: fused masked softmax + attention@V + ELU, flash-style.
// Block: 256 threads, IBLK=16 rows, k-tiles of KT=64.
// Fixed per-row subtractor m_i = lrelu(s1_i + max_k s2_k) >= true row max
// (lrelu monotone) -> single pass, no rescale, masked entries contribute 0.
// ---------------------------------------------------------------------------
#define IBLK 16
#define KT 64

__global__ __launch_bounds__(256) void k_attn(
    const int* __restrict__ adj, const float* __restrict__ V,
    const float* __restrict__ s1g, const float* __restrict__ s2g,
    float* __restrict__ out)
{
    __shared__ float s2_lds[NN];                       // 8 KB
    __shared__ __align__(16) float P_lds[IBLK][KT];    // 4 KB
    __shared__ float s1_lds[IBLK];
    __shared__ float rowsum[IBLK];
    __shared__ float wmax[4];

    const int t = threadIdx.x;
    const int blk = blockIdx.x;            // over B*N/IBLK
    const int b = blk / (NN / IBLK);
    const int i0 = (blk % (NN / IBLK)) * IBLK;

    // Stage s2 row for this batch; track its max.
    const float* s2b = s2g + b * NN;
    float lmax = -1e30f;
    for (int idx = t; idx < NN; idx += 256) {
        const float v = s2b[idx];
        s2_lds[idx] = v;
        lmax = fmaxf(lmax, v);
    }
    if (t < IBLK) s1_lds[t] = s1g[b * NN + i0 + t];
#pragma unroll
    for (int off = 32; off; off >>= 1) lmax = fmaxf(lmax, __shfl_down(lmax, off));
    if ((t & 63) == 0) wmax[t >> 6] = lmax;
    __syncthreads();
    const float s2max = fmaxf(fmaxf(wmax[0], wmax[1]), fmaxf(wmax[2], wmax[3]));

    const int lane = t & 63;
    const int g = t >> 6;  // wave id 0..3

    // Per-row fixed subtractors for the 4 rows this wave computes in phase A.
    float mA[4];
#pragma unroll
    for (int pp = 0; pp < 4; ++pp) {
        const float x = s1_lds[pp * 4 + g] + s2max;
        mA[pp] = fmaxf(x, ALPHA * x);
    }

    float2 acc[4];  // phase-B rows g*4+rr, out cols 2*lane, 2*lane+1
#pragma unroll
    for (int rr = 0; rr < 4; ++rr) acc[rr] = make_float2(0.f, 0.f);
    float sumacc[4] = {0.f, 0.f, 0.f, 0.f};  // per-lane partial softmax sums

    const int* adjb = adj + ((long long)b * NN + i0) * NN;
    const float2* Vb = (const float2*)V + (size_t)b * NN * (OUT_F / 2);

    for (int k0 = 0; k0 < NN; k0 += KT) {
        // ---- phase A: P tile (16 rows x 64 k), wave g does rows pp*4+g ----
#pragma unroll
        for (int pp = 0; pp < 4; ++pp) {
            const int row = pp * 4 + g;
            const int adjv = adjb[(long long)row * NN + k0 + lane];
            float e = s1_lds[row] + s2_lds[k0 + lane];
            e = fmaxf(e, ALPHA * e);  // leaky_relu
            const float p = (adjv > 0) ? __expf(e - mA[pp]) : 0.f;
            sumacc[pp] += p;
            P_lds[row][lane] = p;
        }
        __syncthreads();

        // ---- phase B: acc += P[g*4+rr][k] * V[k][2*lane..2*lane+1] ----
#pragma unroll 4
        for (int k4 = 0; k4 < KT / 4; ++k4) {
            const int kk = k0 + 4 * k4;
            const float2 v0 = Vb[(size_t)(kk + 0) * (OUT_F / 2) + lane];
            const float2 v1 = Vb[(size_t)(kk + 1) * (OUT_F / 2) + lane];
            const float2 v2 = Vb[(size_t)(kk + 2) * (OUT_F / 2) + lane];
            const float2 v3 = Vb[(size_t)(kk + 3) * (OUT_F / 2) + lane];
#pragma unroll
            for (int rr = 0; rr < 4; ++rr) {
                const float4 p4 = *(const float4*)&P_lds[g * 4 + rr][4 * k4];
                acc[rr].x = fmaf(p4.x, v0.x, acc[rr].x);
                acc[rr].y = fmaf(p4.x, v0.y, acc[rr].y);
                acc[rr].x = fmaf(p4.y, v1.x, acc[rr].x);
                acc[rr].y = fmaf(p4.y, v1.y, acc[rr].y);
                acc[rr].x = fmaf(p4.z, v2.x, acc[rr].x);
                acc[rr].y = fmaf(p4.z, v2.y, acc[rr].y);
                acc[rr].x = fmaf(p4.w, v3.x, acc[rr].x);
                acc[rr].y = fmaf(p4.w, v3.y, acc[rr].y);
            }
        }
        __syncthreads();  // P_lds reused next tile
    }

    // Reduce per-lane softmax partial sums -> rowsum (row pp*4+g per wave).
#pragma unroll
    for (int pp = 0; pp < 4; ++pp) {
        float s = sumacc[pp];
#pragma unroll
        for (int off = 32; off; off >>= 1) s += __shfl_down(s, off);
        if (lane == 0) rowsum[pp * 4 + g] = s;
    }
    __syncthreads();

    // Epilogue: normalize, ELU, store.
#pragma unroll
    for (int rr = 0; rr < 4; ++rr) {
        const int row = g * 4 + rr;
        const float inv = 1.0f / rowsum[row];
        float x = acc[rr].x * inv;
        float y = acc[rr].y * inv;
        x = (x > 0.f) ? x : expm1f(x);
        y = (y > 0.f) ? y : expm1f(y);
        float2* ob = (float2*)out + ((size_t)b * NN + i0 + row) * (OUT_F / 2) + lane;
        *ob = make_float2(x, y);
    }
}

// ---------------------------------------------------------------------------
extern "C" void kernel_launch(void* const* d_in, const int* in_sizes, int n_in,
                              void* d_out, int out_size, void* d_ws, size_t ws_size,
                              hipStream_t stream) {
    const float* h  = (const float*)d_in[0];
    const float* j  = (const float*)d_in[1];
    const int* adj  = (const int*)d_in[2];
    const float* W1 = (const float*)d_in[3];
    const float* W2 = (const float*)d_in[4];
    const float* a  = (const float*)d_in[5];
    float* out = (float*)d_out;

    float* V  = (float*)d_ws;                       // B*N*OUT_F floats (8 MB)
    float* s1 = V + (size_t)BATCH * NN * OUT_F;     // B*N floats
    float* s2 = s1 + (size_t)BATCH * NN;            // B*N floats

    k_proj<<<(BATCH * NN) / ROWS1, 256, 0, stream>>>(h, j, W1, W2, a, V, s1, s2);
    k_attn<<<(BATCH * NN) / IBLK, 256, 0, stream>>>(adj, V, s1, s2, out);
}

// Round 2
// 184.842 us; speedup vs baseline: 1.6829x; 1.6829x over previous
//
#include <hip/hip_runtime.h>
#include <hip/hip_bf16.h>

// Problem constants
#define BATCH 8
#define NN 2048
#define IN_F 256
#define OUT_F 128
#define ALPHA 0.2f

typedef __attribute__((ext_vector_type(8))) short short8v;
typedef __attribute__((ext_vector_type(4))) float f32x4;

// exact RTNE f32 -> bf16 bits
static __device__ __forceinline__ unsigned short f2bf(float x) {
    unsigned int u = __float_as_uint(x);
    u = (u + 0x7fffu + ((u >> 16) & 1u)) >> 16;
    return (unsigned short)u;
}

// ---------------------------------------------------------------------------
// Kernel 1: projections.
//   Wh = h @ W1, Wj = j @ W2   (per-row GEMV, K=256, 128 outputs)
//   Vt = (Wh + Wj)^T  bf16     -> ws   [B][OUT_F][N]   (MFMA-B-fragment friendly)
//   s1 = Wh . a[:128]          -> ws
//   s2 = Wh . a[128:]          -> ws
// ---------------------------------------------------------------------------
#define ROWS1 16

__global__ __launch_bounds__(256) void k_proj(
    const float* __restrict__ h, const float* __restrict__ j,
    const float* __restrict__ W1, const float* __restrict__ W2,
    const float* __restrict__ a,
    unsigned short* __restrict__ Vt, float* __restrict__ s1, float* __restrict__ s2)
{
    __shared__ float h_lds[ROWS1 * IN_F];    // 16 KB
    __shared__ float j_lds[ROWS1 * IN_F];    // 16 KB
    __shared__ float wh_lds[ROWS1 * OUT_F];  // 8 KB
    __shared__ float a_lds[2 * OUT_F];       // 1 KB

    const int t = threadIdx.x;
    const long long row0 = (long long)blockIdx.x * ROWS1;  // global row = b*N + n
    const int b  = (int)(row0 / NN);
    const int n0 = (int)(row0 % NN);

    const float* hbase = h + row0 * IN_F;
    const float* jbase = j + row0 * IN_F;
    for (int idx = t; idx < ROWS1 * IN_F; idx += 256) {
        h_lds[idx] = hbase[idx];
        j_lds[idx] = jbase[idx];
    }
    if (t < 2 * OUT_F) a_lds[t] = a[t];
    __syncthreads();

    const int o  = t & (OUT_F - 1);
    const int hf = t >> 7;  // 0 or 1 -> rows hf*8 .. hf*8+7

    float acch[8], accj[8];
#pragma unroll
    for (int r = 0; r < 8; ++r) { acch[r] = 0.f; accj[r] = 0.f; }

    const float* w1p = W1 + o;  // W1[k][o], stride OUT_F
    const float* w2p = W2 + o;

#pragma unroll 4
    for (int k = 0; k < IN_F; ++k) {
        const float w1 = w1p[k * OUT_F];
        const float w2 = w2p[k * OUT_F];
#pragma unroll
        for (int r = 0; r < 8; ++r) {
            const float hv = h_lds[(hf * 8 + r) * IN_F + k];  // LDS broadcast
            const float jv = j_lds[(hf * 8 + r) * IN_F + k];
            acch[r] = fmaf(hv, w1, acch[r]);
            accj[r] = fmaf(jv, w2, accj[r]);
        }
    }

    // Vt[b][o][n0+hf*8 .. +7]  : 8 consecutive bf16 = one 16B store
    union { short8v v; unsigned short u[8]; } vpk;
#pragma unroll
    for (int r = 0; r < 8; ++r) {
        const int rr = hf * 8 + r;
        wh_lds[rr * OUT_F + o] = acch[r];
        vpk.u[r] = f2bf(acch[r] + accj[r]);
    }
    *(short8v*)(Vt + ((size_t)b * OUT_F + o) * NN + n0 + hf * 8) = vpk.v;
    __syncthreads();

    // s1/s2: dot(Wh[row], a1/a2). Wave w reduces rows 4w..4w+3.
    const int wave = t >> 6, lane = t & 63;
#pragma unroll
    for (int q = 0; q < 4; ++q) {
        const int rr = wave * 4 + q;
        float v1 = wh_lds[rr * OUT_F + lane] * a_lds[lane]
                 + wh_lds[rr * OUT_F + lane + 64] * a_lds[lane + 64];
        float v2 = wh_lds[rr * OUT_F + lane] * a_lds[OUT_F + lane]
                 + wh_lds[rr * OUT_F + lane + 64] * a_lds[OUT_F + lane + 64];
#pragma unroll
        for (int off = 32; off; off >>= 1) {
            v1 += __shfl_down(v1, off);
            v2 += __shfl_down(v2, off);
        }
        if (lane == 0) { s1[row0 + rr] = v1; s2[row0 + rr] = v2; }
    }
}

// ---------------------------------------------------------------------------
// Kernel 2: fused masked softmax + attention@V + ELU, flash-style, bf16 MFMA.
// Block: 256 threads (4 waves, 2x2 grid), IBLK=32 rows, k-tiles of KT=128.
// Fixed per-row subtractor m_i = lrelu(s1_i + max_k s2_k) >= true row max
// (lrelu monotone) -> single pass, no rescale, masked entries contribute 0.
// P tile bf16 in XOR-swizzled LDS; V read as MFMA B-fragments from bf16 Vt.
// adj for tile t+1 prefetched into registers during tile t's MFMA phase.
// ---------------------------------------------------------------------------
#define IBLK 32
#define KT 128

__global__ __launch_bounds__(256) void k_attn(
    const int* __restrict__ adj, const unsigned short* __restrict__ Vt,
    const float* __restrict__ s1g, const float* __restrict__ s2g,
    float* __restrict__ out)
{
    __shared__ float s2_lds[NN];                         // 8 KB
    __shared__ __align__(16) unsigned short P_lds[IBLK * KT];  // 8 KB, XOR-swizzled
    __shared__ float s1_lds[IBLK];
    __shared__ float rowsum[IBLK];
    __shared__ float wmaxs[4];

    const int t = threadIdx.x;
    const int blk = blockIdx.x;               // over B*N/IBLK
    const int b = blk / (NN / IBLK);
    const int i0 = (blk % (NN / IBLK)) * IBLK;

    // ---- phase-A mapping: thread -> (row, 16-wide k-chunk) ----
    const int arow = t >> 3;   // 0..31
    const int akc  = t & 7;    // k = akc*16 .. akc*16+15 within tile
    const int* adjp = adj + ((size_t)b * NN + i0 + arow) * NN + akc * 16;

    // prefetch adj tile 0 while we stage s2
    int4 areg[4];
    {
        const int4* ap = (const int4*)adjp;
        areg[0] = ap[0]; areg[1] = ap[1]; areg[2] = ap[2]; areg[3] = ap[3];
    }

    // ---- stage s2 row for this batch; track its max ----
    const float* s2b = s2g + b * NN;
    float lmax = -1e30f;
    for (int idx = t; idx < NN; idx += 256) {
        const float v = s2b[idx];
        s2_lds[idx] = v;
        lmax = fmaxf(lmax, v);
    }
    if (t < IBLK) s1_lds[t] = s1g[b * NN + i0 + t];
#pragma unroll
    for (int off = 32; off; off >>= 1) lmax = fmaxf(lmax, __shfl_down(lmax, off));
    if ((t & 63) == 0) wmaxs[t >> 6] = lmax;
    __syncthreads();
    const float s2max = fmaxf(fmaxf(wmaxs[0], wmaxs[1]), fmaxf(wmaxs[2], wmaxs[3]));

    const float s1r = s1_lds[arow];
    const float mx  = s1r + s2max;
    const float mA  = fmaxf(mx, ALPHA * mx);  // fixed subtractor for this row

    // ---- MFMA mapping: 2x2 wave grid; wave (wm,wn) owns rows wm*16..+15,
    //      cols wn*64..+63 of the 32x128 output tile ----
    const int lane = t & 63;
    const int wid = t >> 6;
    const int wm = wid >> 1, wn = wid & 1;

    const int rowA = wm * 16 + (lane & 15);
    const int swzA = (rowA & 7) << 4;
    const int baseA = rowA * (KT * 2) + ((lane >> 4) * 16);  // byte addr, pre-swizzle

    const unsigned short* vlane =
        Vt + (size_t)b * OUT_F * NN + (size_t)(wn * 64 + (lane & 15)) * NN + ((lane >> 4) * 8);

    f32x4 acc[4];
#pragma unroll
    for (int f = 0; f < 4; ++f) acc[f] = (f32x4){0.f, 0.f, 0.f, 0.f};

    float psum = 0.f;
    const int wbyte = arow * (KT * 2) + akc * 32;  // phase-A write base (pre-swizzle)
    const int swzW = (arow & 7) << 4;

    for (int tk = 0; tk < NN / KT; ++tk) {
        const int k0 = tk * KT;

        // ---- phase A: P[32][128] bf16 tile (consumes areg) ----
        union { short8v v; unsigned short u[8]; } p0, p1;
        {
            const int* av = (const int*)areg;
            const float* s2p = s2_lds + k0 + akc * 16;
#pragma unroll
            for (int q = 0; q < 16; ++q) {
                float e = s1r + s2p[q];
                e = fmaxf(e, ALPHA * e);                 // leaky_relu
                const float p = (av[q] > 0) ? __expf(e - mA) : 0.f;
                psum += p;
                if (q < 8) p0.u[q] = f2bf(p); else p1.u[q - 8] = f2bf(p);
            }
        }
        *(short8v*)((char*)P_lds + ((wbyte) ^ swzW))      = p0.v;
        *(short8v*)((char*)P_lds + ((wbyte + 16) ^ swzW)) = p1.v;
        __syncthreads();

        // ---- prefetch next adj tile (latency hides under MFMA phase) ----
        if (tk + 1 < NN / KT) {
            const int4* ap = (const int4*)(adjp + (tk + 1) * KT);
            areg[0] = ap[0]; areg[1] = ap[1]; areg[2] = ap[2]; areg[3] = ap[3];
        }

        // ---- phase B: acc += P_tile @ V_tile via MFMA 16x16x32 ----
#pragma unroll
        for (int s = 0; s < 4; ++s) {
            const short8v af = *(const short8v*)((const char*)P_lds + ((baseA + s * 64) ^ swzA));
            const unsigned short* vk = vlane + k0 + s * 32;
#pragma unroll
            for (int f = 0; f < 4; ++f) {
                const short8v bf = *(const short8v*)(vk + (size_t)f * 16 * NN);
                acc[f] = __builtin_amdgcn_mfma_f32_16x16x32_bf16(af, bf, acc[f], 0, 0, 0);
            }
        }
        __syncthreads();  // P_lds reused next tile
    }

    // ---- softmax row sums: reduce over the 8 threads of each row ----
    psum += __shfl_xor(psum, 1);
    psum += __shfl_xor(psum, 2);
    psum += __shfl_xor(psum, 4);
    if (akc == 0) rowsum[arow] = psum;
    __syncthreads();

    // ---- epilogue: normalize, ELU, store (C frag: col=lane&15, row=(lane>>4)*4+r) ----
#pragma unroll
    for (int f = 0; f < 4; ++f) {
#pragma unroll
        for (int r = 0; r < 4; ++r) {
            const int row = wm * 16 + (lane >> 4) * 4 + r;
            const int col = wn * 64 + f * 16 + (lane & 15);
            float x = acc[f][r] / rowsum[row];
            x = (x > 0.f) ? x : expm1f(x);
            out[((size_t)b * NN + i0 + row) * OUT_F + col] = x;
        }
    }
}

// ---------------------------------------------------------------------------
extern "C" void kernel_launch(void* const* d_in, const int* in_sizes, int n_in,
                              void* d_out, int out_size, void* d_ws, size_t ws_size,
                              hipStream_t stream) {
    const float* h  = (const float*)d_in[0];
    const float* j  = (const float*)d_in[1];
    const int* adj  = (const int*)d_in[2];
    const float* W1 = (const float*)d_in[3];
    const float* W2 = (const float*)d_in[4];
    const float* a  = (const float*)d_in[5];
    float* out = (float*)d_out;

    unsigned short* Vt = (unsigned short*)d_ws;               // B*OUT_F*N bf16 (4 MB)
    float* s1 = (float*)((char*)d_ws + (size_t)BATCH * OUT_F * NN * 2);
    float* s2 = s1 + (size_t)BATCH * NN;

    k_proj<<<(BATCH * NN) / ROWS1, 256, 0, stream>>>(h, j, W1, W2, a, Vt, s1, s2);
    k_attn<<<(BATCH * NN) / IBLK, 256, 0, stream>>>(adj, Vt, s1, s2, out);
}

// Round 3
// 107.084 us; speedup vs baseline: 2.9049x; 1.7261x over previous
//
#include <hip/hip_runtime.h>
#include <hip/hip_bf16.h>

// Problem constants
#define BATCH 8
#define NN 2048
#define IN_F 256
#define OUT_F 128
#define ALPHA 0.2f

typedef __attribute__((ext_vector_type(8))) short short8v;
typedef __attribute__((ext_vector_type(4))) float f32x4;

// exact RTNE f32 -> bf16 bits
static __device__ __forceinline__ unsigned short f2bf(float x) {
    unsigned int u = __float_as_uint(x);
    u = (u + 0x7fffu + ((u >> 16) & 1u)) >> 16;
    return (unsigned short)u;
}

// ---------------------------------------------------------------------------
// Kernel 0: weight prep.
//   Wt[o][k] = bf16(Wcat[k][o]),  Wcat = [W1; W2]  (k in 0..511)  -> B-frag friendly
//   w1a1[k] = sum_o W1[k][o] * a[o]        (f32)
//   w1a2[k] = sum_o W1[k][o] * a[128+o]    (f32)
// (s1 = Wh.a1 == h.(W1 a1): fold the attention vectors through W1 once.)
// grid 64 x 256
// ---------------------------------------------------------------------------
__global__ __launch_bounds__(256) void k_prew(
    const float* __restrict__ W1, const float* __restrict__ W2,
    const float* __restrict__ a,
    unsigned short* __restrict__ Wt, float* __restrict__ w1a1, float* __restrict__ w1a2)
{
    const int t = threadIdx.x;
    const int k8 = blockIdx.x * 8;
#pragma unroll
    for (int q = 0; q < 4; ++q) {
        const int idx = q * 256 + t;
        const int o = idx & 127;
        const int kk = k8 + (idx >> 7);
        const float v = (kk < IN_F) ? W1[kk * OUT_F + o] : W2[(kk - IN_F) * OUT_F + o];
        Wt[(size_t)o * 512 + kk] = f2bf(v);
    }
    if (k8 < IN_F) {
        const int lane = t & 63, w = t >> 6;
#pragma unroll
        for (int u = 0; u < 2; ++u) {
            const int kk = k8 + 2 * w + u;
            const float* wr = W1 + kk * OUT_F;
            float v1 = wr[lane] * a[lane] + wr[lane + 64] * a[lane + 64];
            float v2 = wr[lane] * a[OUT_F + lane] + wr[lane + 64] * a[OUT_F + lane + 64];
#pragma unroll
            for (int off = 32; off; off >>= 1) {
                v1 += __shfl_xor(v1, off);
                v2 += __shfl_xor(v2, off);
            }
            if (lane == 0) { w1a1[kk] = v1; w1a2[kk] = v2; }
        }
    }
}

// ---------------------------------------------------------------------------
// Kernel 1: projections via bf16 MFMA.
//   X = [h | j] bf16 staged in XOR-swizzled LDS (16 rows x 512 k)
//   V = X @ Wcat -> Vt[b][o][n] bf16    (D tile: M=row(n), N=col(o))
//   s1 = h . w1a1, s2 = h . w1a2 (f32, fused into the staging pass)
// Block: 256 thr, BM=16 rows, 4 waves each own 32 out-cols, full K.
// grid 1024 x 256
// ---------------------------------------------------------------------------
#define BM 16

__global__ __launch_bounds__(256) void k_proj(
    const float* __restrict__ h, const float* __restrict__ j,
    const unsigned short* __restrict__ Wt,
    const float* __restrict__ w1a1g, const float* __restrict__ w1a2g,
    unsigned short* __restrict__ Vt, float* __restrict__ s1, float* __restrict__ s2)
{
    __shared__ __align__(16) unsigned short X[BM * 512];  // 16 KB, XOR-swizzled

    const int t = threadIdx.x, lane = t & 63, w = t >> 6;
    const int row0 = blockIdx.x * BM;          // global flat row = b*N + n
    const int b = row0 >> 11, n0 = row0 & 2047;

    const float4* wa1v = (const float4*)w1a1g;
    const float4* wa2v = (const float4*)w1a2g;

    // ---- stage h (k 0..255) + fused s-dots; rows: idx>>6 == q*4+w per wave ----
#pragma unroll
    for (int q = 0; q < 4; ++q) {
        const int idx = q * 256 + t;
        const int row = idx >> 6, f4 = idx & 63;
        const float4 hv = ((const float4*)(h + (size_t)(row0 + row) * IN_F))[f4];
        union { unsigned long long ll; unsigned short u[4]; } pk;
        pk.u[0] = f2bf(hv.x); pk.u[1] = f2bf(hv.y); pk.u[2] = f2bf(hv.z); pk.u[3] = f2bf(hv.w);
        *(unsigned long long*)((char*)X + ((row * 1024 + f4 * 8) ^ ((row & 7) << 4))) = pk.ll;
        const float4 a1 = wa1v[f4], a2 = wa2v[f4];
        float d1 = hv.x * a1.x + hv.y * a1.y + hv.z * a1.z + hv.w * a1.w;
        float d2 = hv.x * a2.x + hv.y * a2.y + hv.z * a2.z + hv.w * a2.w;
#pragma unroll
        for (int off = 32; off; off >>= 1) {
            d1 += __shfl_xor(d1, off);
            d2 += __shfl_xor(d2, off);
        }
        if (lane == 0) { s1[row0 + row] = d1; s2[row0 + row] = d2; }
    }
    // ---- stage j (k 256..511) ----
#pragma unroll
    for (int q = 0; q < 4; ++q) {
        const int idx = q * 256 + t;
        const int row = idx >> 6, f4 = idx & 63;
        const float4 jv = ((const float4*)(j + (size_t)(row0 + row) * IN_F))[f4];
        union { unsigned long long ll; unsigned short u[4]; } pk;
        pk.u[0] = f2bf(jv.x); pk.u[1] = f2bf(jv.y); pk.u[2] = f2bf(jv.z); pk.u[3] = f2bf(jv.w);
        *(unsigned long long*)((char*)X + ((row * 1024 + 512 + f4 * 8) ^ ((row & 7) << 4))) = pk.ll;
    }
    __syncthreads();

    // ---- MFMA: D[m=row][n=o], A = X (LDS), B = Wt (L2-hot global) ----
    const unsigned short* wb = Wt + (size_t)(w * 32 + (lane & 15)) * 512 + ((lane >> 4) * 8);
    const int abase = (lane & 15) * 1024 + ((lane >> 4) * 16);
    const int aswz = (lane & 7) << 4;

    f32x4 acc0 = {0.f, 0.f, 0.f, 0.f}, acc1 = {0.f, 0.f, 0.f, 0.f};
#pragma unroll
    for (int ks = 0; ks < 16; ++ks) {
        const short8v af = *(const short8v*)((const char*)X + ((abase + ks * 64) ^ aswz));
        const short8v b0 = *(const short8v*)(wb + ks * 32);
        const short8v b1 = *(const short8v*)(wb + 16 * 512 + ks * 32);
        acc0 = __builtin_amdgcn_mfma_f32_16x16x32_bf16(af, b0, acc0, 0, 0, 0);
        acc1 = __builtin_amdgcn_mfma_f32_16x16x32_bf16(af, b1, acc1, 0, 0, 0);
    }

    // ---- store Vt[b][o][n]: lane holds rows n0+(lane>>4)*4+r, col o fixed ----
    const int nr = (lane >> 4) * 4;
#pragma unroll
    for (int f = 0; f < 2; ++f) {
        const f32x4 ac = f ? acc1 : acc0;
        const int o = w * 32 + f * 16 + (lane & 15);
        union { unsigned long long ll; unsigned short u[4]; } pk;
#pragma unroll
        for (int r = 0; r < 4; ++r) pk.u[r] = f2bf(ac[r]);
        *(unsigned long long*)(Vt + ((size_t)b * OUT_F + o) * NN + n0 + nr) = pk.ll;
    }
}

// ---------------------------------------------------------------------------
// Kernel 2: fused masked softmax + attention@V + ELU. No main-loop barriers.
// D[o][i] = sum_k Vt[o][k] * P[i][k]:  A = Vt frag (16B global, L2-resident),
// B = P frag produced IN REGISTERS (lane owns row i=lane&15, k-strip (lane>>4)*8).
// 4 waves split k (512 each); end-of-kernel LDS combine. IBLK=16, grid 1024.
// Fixed subtractor m_i = lrelu(s1_i + max_k s2_k) -> single pass, no rescale.
// adj register-pipelined 2 steps deep.
// ---------------------------------------------------------------------------
#define COMBSZ (4 * OUT_F * 17)

__global__ __launch_bounds__(256) void k_attn(
    const int* __restrict__ adj, const unsigned short* __restrict__ Vt,
    const float* __restrict__ s1g, const float* __restrict__ s2g,
    float* __restrict__ out)
{
    __shared__ __align__(16) float lds[COMBSZ];  // 34816 B: s2 stage, then combine
    __shared__ float rs_lds[4 * 16];
    __shared__ float wmaxs[4];

    const int t = threadIdx.x, lane = t & 63, w = t >> 6;
    // XCD-bijective swizzle (grid 1024 % 8 == 0): each XCD owns one batch.
    const int orig = blockIdx.x;
    const int blk = (orig & 7) * 128 + (orig >> 3);
    const int b = blk >> 7;
    const int i0 = (blk & 127) << 4;

    // ---- stage s2 (full row, 8 KB) + global max ----
    float* s2_lds = lds;
    const float4* s2v = (const float4*)(s2g + b * NN);
    float lmax = -1e30f;
#pragma unroll
    for (int q = 0; q < 2; ++q) {
        const int idx = q * 256 + t;
        const float4 v = s2v[idx];
        ((float4*)s2_lds)[idx] = v;
        lmax = fmaxf(fmaxf(lmax, fmaxf(v.x, v.y)), fmaxf(v.z, v.w));
    }
#pragma unroll
    for (int off = 32; off; off >>= 1) lmax = fmaxf(lmax, __shfl_xor(lmax, off));
    if (lane == 0) wmaxs[w] = lmax;

    const int irow = lane & 15;                 // this lane's output row i (local)
    const float s1r = s1g[b * NN + i0 + irow];
    __syncthreads();
    const float s2max = fmaxf(fmaxf(wmaxs[0], wmaxs[1]), fmaxf(wmaxs[2], wmaxs[3]));
    const float mx = s1r + s2max;
    const float mA = fmaxf(mx, ALPHA * mx);     // fixed subtractor, >= true row max

    const int kw = w * 512;                     // this wave's k-range
    const int kc = (lane >> 4) * 8;             // k-strip within a 32-step
    const int* adjp = adj + ((size_t)b * NN + i0 + irow) * NN + kw + kc;
    const float* s2p = s2_lds + kw + kc;
    const unsigned short* vb = Vt + ((size_t)b * OUT_F + (lane & 15)) * NN + kw + kc;

    f32x4 acc[8];
#pragma unroll
    for (int og = 0; og < 8; ++og) acc[og] = (f32x4){0.f, 0.f, 0.f, 0.f};
    float psum = 0.f;

    // ---- adj register pipeline, depth 2 ----
    int4 a0a = ((const int4*)adjp)[0];
    int4 a0b = ((const int4*)(adjp + 4))[0];
    int4 a1a = ((const int4*)(adjp + 32))[0];
    int4 a1b = ((const int4*)(adjp + 36))[0];

#pragma unroll 2
    for (int ks = 0; ks < 16; ++ks) {
        int4 ca, cb;
        if ((ks & 1) == 0) { ca = a0a; cb = a0b; } else { ca = a1a; cb = a1b; }
        if (ks + 2 < 16) {
            const int4* np = (const int4*)(adjp + (ks + 2) * 32);
            if ((ks & 1) == 0) { a0a = np[0]; a0b = np[1]; }
            else               { a1a = np[0]; a1b = np[1]; }
        }
        const int avs[8] = {ca.x, ca.y, ca.z, ca.w, cb.x, cb.y, cb.z, cb.w};
        const float* s2k = s2p + ks * 32;
        union { short8v v; unsigned short u[8]; } pb;
#pragma unroll
        for (int e = 0; e < 8; ++e) {
            float ee = s1r + s2k[e];
            ee = fmaxf(ee, ALPHA * ee);          // leaky_relu
            float pv = __expf(ee - mA);
            pv = (avs[e] > 0) ? pv : 0.f;
            psum += pv;
            pb.u[e] = f2bf(pv);
        }
        const unsigned short* vk = vb + ks * 32;
#pragma unroll
        for (int og = 0; og < 8; ++og) {
            const short8v av8 = *(const short8v*)(vk + (size_t)og * 16 * NN);
            acc[og] = __builtin_amdgcn_mfma_f32_16x16x32_bf16(av8, pb.v, acc[og], 0, 0, 0);
        }
    }

    // ---- row-sum: 4 k-strips of this wave -> every lane holds wave partial ----
    psum += __shfl_xor(psum, 16);
    psum += __shfl_xor(psum, 32);

    __syncthreads();  // s2_lds no longer needed; reuse as combine buffer
    float* comb = lds; // [4][OUT_F][17]
#pragma unroll
    for (int og = 0; og < 8; ++og) {
        const int obase = og * 16 + (lane >> 4) * 4;
#pragma unroll
        for (int r = 0; r < 4; ++r)
            comb[(w * OUT_F + obase + r) * 17 + irow] = acc[og][r];
    }
    if (lane < 16) rs_lds[w * 16 + lane] = psum;
    __syncthreads();

    // ---- combine 4 wave-partials, normalize, ELU, coalesced f32 store ----
    const int i = t >> 4, oc = t & 15;
    const float tot = rs_lds[i] + rs_lds[16 + i] + rs_lds[32 + i] + rs_lds[48 + i];
    const float inv = 1.0f / tot;
    float res[8];
#pragma unroll
    for (int u = 0; u < 8; ++u) {
        const int o = oc * 8 + u;
        float v = comb[o * 17 + i] + comb[(OUT_F + o) * 17 + i]
                + comb[(2 * OUT_F + o) * 17 + i] + comb[(3 * OUT_F + o) * 17 + i];
        v *= inv;
        res[u] = (v > 0.f) ? v : expm1f(v);
    }
    float4* ob = (float4*)(out + ((size_t)b * NN + i0 + i) * OUT_F + oc * 8);
    ob[0] = make_float4(res[0], res[1], res[2], res[3]);
    ob[1] = make_float4(res[4], res[5], res[6], res[7]);
}

// ---------------------------------------------------------------------------
extern "C" void kernel_launch(void* const* d_in, const int* in_sizes, int n_in,
                              void* d_out, int out_size, void* d_ws, size_t ws_size,
                              hipStream_t stream) {
    const float* h  = (const float*)d_in[0];
    const float* j  = (const float*)d_in[1];
    const int* adj  = (const int*)d_in[2];
    const float* W1 = (const float*)d_in[3];
    const float* W2 = (const float*)d_in[4];
    const float* a  = (const float*)d_in[5];
    float* out = (float*)d_out;

    char* ws = (char*)d_ws;
    unsigned short* Vt = (unsigned short*)ws;               // 8*128*2048*2 = 4 MB
    ws += (size_t)BATCH * OUT_F * NN * 2;
    float* s1 = (float*)ws; ws += (size_t)BATCH * NN * 4;   // 64 KB
    float* s2 = (float*)ws; ws += (size_t)BATCH * NN * 4;   // 64 KB
    unsigned short* Wt = (unsigned short*)ws; ws += 128 * 512 * 2;  // 128 KB
    float* w1a1 = (float*)ws; ws += 512 * 4;
    float* w1a2 = (float*)ws;

    k_prew<<<64, 256, 0, stream>>>(W1, W2, a, Wt, w1a1, w1a2);
    k_proj<<<(BATCH * NN) / BM, 256, 0, stream>>>(h, j, Wt, w1a1, w1a2, Vt, s1, s2);
    k_attn<<<(BATCH * NN) / 16, 256, 0, stream>>>(adj, Vt, s1, s2, out);
}

// Round 4
// 87.358 us; speedup vs baseline: 3.5609x; 1.2258x over previous
//
#include <hip/hip_runtime.h>
#include <hip/hip_bf16.h>

// Problem constants
#define BATCH 8
#define NN 2048
#define IN_F 256
#define OUT_F 128
#define ALPHA 0.2f

typedef __attribute__((ext_vector_type(8))) short short8v;
typedef __attribute__((ext_vector_type(4))) float f32x4;

// exact RTNE f32 -> bf16 bits
static __device__ __forceinline__ unsigned short f2bf(float x) {
    unsigned int u = __float_as_uint(x);
    u = (u + 0x7fffu + ((u >> 16) & 1u)) >> 16;
    return (unsigned short)u;
}

// ---------------------------------------------------------------------------
// Kernel 0: weight prep.
//   Wt[o][k] = bf16(Wcat[k][o]),  Wcat = [W1; W2]  (k in 0..511)
//   w1a1[k] = sum_o W1[k][o] * a[o],  w1a2[k] = sum_o W1[k][o] * a[128+o]
// ---------------------------------------------------------------------------
__global__ __launch_bounds__(256) void k_prew(
    const float* __restrict__ W1, const float* __restrict__ W2,
    const float* __restrict__ a,
    unsigned short* __restrict__ Wt, float* __restrict__ w1a1, float* __restrict__ w1a2)
{
    const int t = threadIdx.x;
    const int k8 = blockIdx.x * 8;
#pragma unroll
    for (int q = 0; q < 4; ++q) {
        const int idx = q * 256 + t;
        const int o = idx & 127;
        const int kk = k8 + (idx >> 7);
        const float v = (kk < IN_F) ? W1[kk * OUT_F + o] : W2[(kk - IN_F) * OUT_F + o];
        Wt[(size_t)o * 512 + kk] = f2bf(v);
    }
    if (k8 < IN_F) {
        const int lane = t & 63, w = t >> 6;
#pragma unroll
        for (int u = 0; u < 2; ++u) {
            const int kk = k8 + 2 * w + u;
            const float* wr = W1 + kk * OUT_F;
            float v1 = wr[lane] * a[lane] + wr[lane + 64] * a[lane + 64];
            float v2 = wr[lane] * a[OUT_F + lane] + wr[lane + 64] * a[OUT_F + lane + 64];
#pragma unroll
            for (int off = 32; off; off >>= 1) {
                v1 += __shfl_xor(v1, off);
                v2 += __shfl_xor(v2, off);
            }
            if (lane == 0) { w1a1[kk] = v1; w1a2[kk] = v2; }
        }
    }
}

// ---------------------------------------------------------------------------
// Kernel 1: projections via bf16 MFMA  +  coalesced adj->bitmask sweep.
//   V = [h|j] @ Wcat -> Vt[b][o][n] bf16 ; s1 = h.w1a1 ; s2 = h.w1a2
//   bits[row][kbyte]: bit e of byte kb = (adj[row][kb*8+e] > 0)
// ---------------------------------------------------------------------------
#define BM 16

__global__ __launch_bounds__(256) void k_proj(
    const float* __restrict__ h, const float* __restrict__ j,
    const unsigned short* __restrict__ Wt,
    const float* __restrict__ w1a1g, const float* __restrict__ w1a2g,
    const int* __restrict__ adj,
    unsigned short* __restrict__ Vt, float* __restrict__ s1, float* __restrict__ s2,
    unsigned short* __restrict__ bits16)
{
    __shared__ __align__(16) unsigned short X[BM * 512];  // 16 KB, XOR-swizzled

    const int t = threadIdx.x, lane = t & 63, w = t >> 6;
    const int row0 = blockIdx.x * BM;
    const int b = row0 >> 11, n0 = row0 & 2047;

    const float4* wa1v = (const float4*)w1a1g;
    const float4* wa2v = (const float4*)w1a2g;

    // ---- stage h (k 0..255) + fused s-dots ----
#pragma unroll
    for (int q = 0; q < 4; ++q) {
        const int idx = q * 256 + t;
        const int row = idx >> 6, f4 = idx & 63;
        const float4 hv = ((const float4*)(h + (size_t)(row0 + row) * IN_F))[f4];
        union { unsigned long long ll; unsigned short u[4]; } pk;
        pk.u[0] = f2bf(hv.x); pk.u[1] = f2bf(hv.y); pk.u[2] = f2bf(hv.z); pk.u[3] = f2bf(hv.w);
        *(unsigned long long*)((char*)X + ((row * 1024 + f4 * 8) ^ ((row & 7) << 4))) = pk.ll;
        const float4 a1 = wa1v[f4], a2 = wa2v[f4];
        float d1 = hv.x * a1.x + hv.y * a1.y + hv.z * a1.z + hv.w * a1.w;
        float d2 = hv.x * a2.x + hv.y * a2.y + hv.z * a2.z + hv.w * a2.w;
#pragma unroll
        for (int off = 32; off; off >>= 1) {
            d1 += __shfl_xor(d1, off);
            d2 += __shfl_xor(d2, off);
        }
        if (lane == 0) { s1[row0 + row] = d1; s2[row0 + row] = d2; }
    }
    // ---- stage j (k 256..511) ----
#pragma unroll
    for (int q = 0; q < 4; ++q) {
        const int idx = q * 256 + t;
        const int row = idx >> 6, f4 = idx & 63;
        const float4 jv = ((const float4*)(j + (size_t)(row0 + row) * IN_F))[f4];
        union { unsigned long long ll; unsigned short u[4]; } pk;
        pk.u[0] = f2bf(jv.x); pk.u[1] = f2bf(jv.y); pk.u[2] = f2bf(jv.z); pk.u[3] = f2bf(jv.w);
        *(unsigned long long*)((char*)X + ((row * 1024 + 512 + f4 * 8) ^ ((row & 7) << 4))) = pk.ll;
    }
    __syncthreads();

    // ---- MFMA: D[m=row][n=o], A = X (LDS), B = Wt (L2-hot global) ----
    const unsigned short* wb = Wt + (size_t)(w * 32 + (lane & 15)) * 512 + ((lane >> 4) * 8);
    const int abase = (lane & 15) * 1024 + ((lane >> 4) * 16);
    const int aswz = (lane & 7) << 4;

    f32x4 acc0 = {0.f, 0.f, 0.f, 0.f}, acc1 = {0.f, 0.f, 0.f, 0.f};
#pragma unroll
    for (int ks = 0; ks < 16; ++ks) {
        const short8v af = *(const short8v*)((const char*)X + ((abase + ks * 64) ^ aswz));
        const short8v b0 = *(const short8v*)(wb + ks * 32);
        const short8v b1 = *(const short8v*)(wb + 16 * 512 + ks * 32);
        acc0 = __builtin_amdgcn_mfma_f32_16x16x32_bf16(af, b0, acc0, 0, 0, 0);
        acc1 = __builtin_amdgcn_mfma_f32_16x16x32_bf16(af, b1, acc1, 0, 0, 0);
    }

    const int nr = (lane >> 4) * 4;
#pragma unroll
    for (int f = 0; f < 2; ++f) {
        const f32x4 ac = f ? acc1 : acc0;
        const int o = w * 32 + f * 16 + (lane & 15);
        union { unsigned long long ll; unsigned short u[4]; } pk;
#pragma unroll
        for (int r = 0; r < 4; ++r) pk.u[r] = f2bf(ac[r]);
        *(unsigned long long*)(Vt + ((size_t)b * OUT_F + o) * NN + n0 + nr) = pk.ll;
    }

    // ---- coalesced adj -> bits sweep (grid-strided; 16 ints -> 16 bits/thread) ----
    // total 16-bit units = B*N*N/16 = 2097152; grid 1024x256 -> 8 iters
    const int gstride = 1024 * 256;
    for (int g = blockIdx.x * 256 + t; g < (BATCH * NN * NN) / 16; g += gstride) {
        const int4* ap = (const int4*)(adj + (size_t)g * 16);
        const int4 x0 = ap[0], x1 = ap[1], x2 = ap[2], x3 = ap[3];
        unsigned m = 0;
        m |= (x0.x > 0) ? 1u : 0u;        m |= (x0.y > 0) ? 2u : 0u;
        m |= (x0.z > 0) ? 4u : 0u;        m |= (x0.w > 0) ? 8u : 0u;
        m |= (x1.x > 0) ? 16u : 0u;       m |= (x1.y > 0) ? 32u : 0u;
        m |= (x1.z > 0) ? 64u : 0u;       m |= (x1.w > 0) ? 128u : 0u;
        m |= (x2.x > 0) ? 256u : 0u;      m |= (x2.y > 0) ? 512u : 0u;
        m |= (x2.z > 0) ? 1024u : 0u;     m |= (x2.w > 0) ? 2048u : 0u;
        m |= (x3.x > 0) ? 4096u : 0u;     m |= (x3.y > 0) ? 8192u : 0u;
        m |= (x3.z > 0) ? 16384u : 0u;    m |= (x3.w > 0) ? 32768u : 0u;
        bits16[g] = (unsigned short)m;
    }
}

// ---------------------------------------------------------------------------
// Kernel 2: fused masked softmax + attention@V + ELU. No main-loop barriers.
// IBLK=32 rows (2 subtiles of 16), 4 waves split k (512 each).
// B-frag P produced in registers; A-frag V from L2, reused across both subtiles.
// adj mask read as pre-compressed bits: 16 u64 preloaded per lane (whole k-range).
// Fixed subtractor m_i = lrelu(s1_i + max_k s2_k) -> single pass, no rescale.
// ---------------------------------------------------------------------------
#define IBLK 32

__global__ __launch_bounds__(256, 3) void k_attn(
    const unsigned char* __restrict__ bits, const unsigned short* __restrict__ Vt,
    const float* __restrict__ s1g, const float* __restrict__ s2g,
    float* __restrict__ out)
{
    __shared__ __align__(16) float s2_lds[NN];       // 8 KB
    __shared__ float comb[4 * OUT_F * 17];           // 34.8 KB
    __shared__ float rs_lds[4][IBLK];
    __shared__ float wmaxs[4];

    const int t = threadIdx.x, lane = t & 63, w = t >> 6;
    // XCD-bijective swizzle (grid 512 % 8 == 0): each XCD owns one batch.
    const int orig = blockIdx.x;
    const int blk = (orig & 7) * 64 + (orig >> 3);
    const int b = blk >> 6;
    const int i0 = (blk & 63) * IBLK;

    const int irow = lane & 15;     // subtile-local row; also o-index low bits for V
    const int kcb = lane >> 4;      // k-strip 0..3 within a 32-k step
    const int kw = w * 512;         // this wave's k-range

    // ---- preload ALL adj bits for this wave's k-range (2 subtiles x 8 u64) ----
    unsigned long long breg0[8], breg1[8];
    {
        const unsigned char* bp0 = bits + ((size_t)b * NN + i0 + irow) * 256 + (kw >> 3);
        const unsigned char* bp1 = bp0 + 16 * 256;
#pragma unroll
        for (int q = 0; q < 8; ++q) {
            breg0[q] = *(const unsigned long long*)(bp0 + q * 8);
            breg1[q] = *(const unsigned long long*)(bp1 + q * 8);
        }
    }

    // ---- stage s2 (full row) + global max ----
    const float4* s2v = (const float4*)(s2g + b * NN);
    float lmax = -1e30f;
#pragma unroll
    for (int q = 0; q < 2; ++q) {
        const int idx = q * 256 + t;
        const float4 v = s2v[idx];
        ((float4*)s2_lds)[idx] = v;
        lmax = fmaxf(fmaxf(lmax, fmaxf(v.x, v.y)), fmaxf(v.z, v.w));
    }
#pragma unroll
    for (int off = 32; off; off >>= 1) lmax = fmaxf(lmax, __shfl_xor(lmax, off));
    if (lane == 0) wmaxs[w] = lmax;

    const float s1r0 = s1g[b * NN + i0 + irow];
    const float s1r1 = s1g[b * NN + i0 + 16 + irow];
    __syncthreads();
    const float s2max = fmaxf(fmaxf(wmaxs[0], wmaxs[1]), fmaxf(wmaxs[2], wmaxs[3]));
    const float mx0 = s1r0 + s2max, mx1 = s1r1 + s2max;
    const float mA0 = fmaxf(mx0, ALPHA * mx0);
    const float mA1 = fmaxf(mx1, ALPHA * mx1);

    const float* s2p = s2_lds + kw + kcb * 8;
    const unsigned short* vb = Vt + ((size_t)b * OUT_F + irow) * NN + kw + kcb * 8;

    f32x4 acc0[8], acc1[8];
#pragma unroll
    for (int og = 0; og < 8; ++og) {
        acc0[og] = (f32x4){0.f, 0.f, 0.f, 0.f};
        acc1[og] = (f32x4){0.f, 0.f, 0.f, 0.f};
    }
    float psum0 = 0.f, psum1 = 0.f;

#pragma unroll
    for (int ks = 0; ks < 16; ++ks) {
        // V fragments for this 32-k step (shared by both row-subtiles)
        short8v vf[8];
#pragma unroll
        for (int og = 0; og < 8; ++og)
            vf[og] = *(const short8v*)(vb + ks * 32 + (size_t)og * 16 * NN);

        const float4 sa = *(const float4*)(s2p + ks * 32);
        const float4 sb = *(const float4*)(s2p + ks * 32 + 4);
        const float s2r[8] = {sa.x, sa.y, sa.z, sa.w, sb.x, sb.y, sb.z, sb.w};

        const unsigned sh = ((ks & 1) << 5) + (kcb << 3);
        const unsigned bb0 = (unsigned)((breg0[ks >> 1] >> sh) & 0xff);
        const unsigned bb1 = (unsigned)((breg1[ks >> 1] >> sh) & 0xff);

        union { short8v v; unsigned short u[8]; } pb0, pb1;
#pragma unroll
        for (int e = 0; e < 8; ++e) {
            float x0 = s1r0 + s2r[e];
            x0 = fmaxf(x0, ALPHA * x0);
            float p0 = __expf(x0 - mA0);
            p0 = (bb0 & (1u << e)) ? p0 : 0.f;
            psum0 += p0;
            pb0.u[e] = f2bf(p0);
            float x1 = s1r1 + s2r[e];
            x1 = fmaxf(x1, ALPHA * x1);
            float p1 = __expf(x1 - mA1);
            p1 = (bb1 & (1u << e)) ? p1 : 0.f;
            psum1 += p1;
            pb1.u[e] = f2bf(p1);
        }
#pragma unroll
        for (int og = 0; og < 8; ++og) {
            acc0[og] = __builtin_amdgcn_mfma_f32_16x16x32_bf16(vf[og], pb0.v, acc0[og], 0, 0, 0);
            acc1[og] = __builtin_amdgcn_mfma_f32_16x16x32_bf16(vf[og], pb1.v, acc1[og], 0, 0, 0);
        }
    }

    // ---- row sums (per wave partial): combine the 4 k-strips ----
    psum0 += __shfl_xor(psum0, 16); psum0 += __shfl_xor(psum0, 32);
    psum1 += __shfl_xor(psum1, 16); psum1 += __shfl_xor(psum1, 32);
    if (lane < 16) { rs_lds[w][irow] = psum0; rs_lds[w][16 + irow] = psum1; }

    // ---- combine round 0 (rows i0..i0+15) ----
#pragma unroll
    for (int og = 0; og < 8; ++og)
#pragma unroll
        for (int r = 0; r < 4; ++r)
            comb[(w * OUT_F + og * 16 + kcb * 4 + r) * 17 + irow] = acc0[og][r];
    __syncthreads();
    {
        const int i = t >> 4, oc = t & 15;
        const float tot = rs_lds[0][i] + rs_lds[1][i] + rs_lds[2][i] + rs_lds[3][i];
        const float inv = 1.0f / tot;
        float res[8];
#pragma unroll
        for (int u = 0; u < 8; ++u) {
            const int o = oc * 8 + u;
            float v = comb[o * 17 + i] + comb[(OUT_F + o) * 17 + i]
                    + comb[(2 * OUT_F + o) * 17 + i] + comb[(3 * OUT_F + o) * 17 + i];
            v *= inv;
            res[u] = (v > 0.f) ? v : expm1f(v);
        }
        float4* ob = (float4*)(out + ((size_t)b * NN + i0 + i) * OUT_F + oc * 8);
        ob[0] = make_float4(res[0], res[1], res[2], res[3]);
        ob[1] = make_float4(res[4], res[5], res[6], res[7]);
    }
    __syncthreads();

    // ---- combine round 1 (rows i0+16..i0+31) ----
#pragma unroll
    for (int og = 0; og < 8; ++og)
#pragma unroll
        for (int r = 0; r < 4; ++r)
            comb[(w * OUT_F + og * 16 + kcb * 4 + r) * 17 + irow] = acc1[og][r];
    __syncthreads();
    {
        const int i = t >> 4, oc = t & 15;
        const float tot = rs_lds[0][16 + i] + rs_lds[1][16 + i] + rs_lds[2][16 + i] + rs_lds[3][16 + i];
        const float inv = 1.0f / tot;
        float res[8];
#pragma unroll
        for (int u = 0; u < 8; ++u) {
            const int o = oc * 8 + u;
            float v = comb[o * 17 + i] + comb[(OUT_F + o) * 17 + i]
                    + comb[(2 * OUT_F + o) * 17 + i] + comb[(3 * OUT_F + o) * 17 + i];
            v *= inv;
            res[u] = (v > 0.f) ? v : expm1f(v);
        }
        float4* ob = (float4*)(out + ((size_t)b * NN + i0 + 16 + i) * OUT_F + oc * 8);
        ob[0] = make_float4(res[0], res[1], res[2], res[3]);
        ob[1] = make_float4(res[4], res[5], res[6], res[7]);
    }
}

// ---------------------------------------------------------------------------
extern "C" void kernel_launch(void* const* d_in, const int* in_sizes, int n_in,
                              void* d_out, int out_size, void* d_ws, size_t ws_size,
                              hipStream_t stream) {
    const float* h  = (const float*)d_in[0];
    const float* j  = (const float*)d_in[1];
    const int* adj  = (const int*)d_in[2];
    const float* W1 = (const float*)d_in[3];
    const float* W2 = (const float*)d_in[4];
    const float* a  = (const float*)d_in[5];
    float* out = (float*)d_out;

    char* ws = (char*)d_ws;
    unsigned short* Vt = (unsigned short*)ws;               // 4 MB
    ws += (size_t)BATCH * OUT_F * NN * 2;
    float* s1 = (float*)ws; ws += (size_t)BATCH * NN * 4;   // 64 KB
    float* s2 = (float*)ws; ws += (size_t)BATCH * NN * 4;   // 64 KB
    unsigned short* Wt = (unsigned short*)ws; ws += 128 * 512 * 2;  // 128 KB
    float* w1a1 = (float*)ws; ws += 512 * 4;
    float* w1a2 = (float*)ws; ws += 512 * 4;
    unsigned char* bits = (unsigned char*)ws;               // B*N*N/8 = 4 MB

    k_prew<<<64, 256, 0, stream>>>(W1, W2, a, Wt, w1a1, w1a2);
    k_proj<<<(BATCH * NN) / BM, 256, 0, stream>>>(h, j, Wt, w1a1, w1a2, adj,
                                                  Vt, s1, s2, (unsigned short*)bits);
    k_attn<<<(BATCH * NN) / IBLK, 256, 0, stream>>>(bits, Vt, s1, s2, out);
}